// Round 1
// baseline (156.518 us; speedup 1.0000x reference)
//
#include <hip/hip_runtime.h>
#include <math.h>

// Problem constants (fixed by setup_inputs)
constexpr int Bc  = 32768;
constexpr int NAc = 60;
constexpr int NRc = 4;

constexpr int WPB    = 4;            // waves per block (256 threads)
constexpr int NBLK   = 2048;         // grid size for main kernel
constexpr int NWAVES = NBLK * WPB;   // 8192 waves -> 4 batch elems per wave

// cos(1.0 rad): mask (gt_bias < 1) <=> clip(0.5*(tr-1)) > cos(1)
#define COS_ONE 0.5403023058681398f

__global__ __launch_bounds__(256) void mtl_main(
    const float* __restrict__ wts,      // (B, NA)
    const int*   __restrict__ label,    // (B,)
    const float* __restrict__ y,        // (B, NR, NA)
    const float* __restrict__ gt_R,     // (B, NA, 3, 3)
    const float* __restrict__ anchors,  // (NA, 3, 3)
    float*       __restrict__ out,      // [loss, cls, w*l2, r_acc, ang_err(B)]
    float*       __restrict__ l2p,      // (NBLK,)
    float*       __restrict__ lpp,      // (NBLK,)
    float*       __restrict__ crp)      // (NBLK,)
{
    const int lane = threadIdx.x & 63;
    const int wave = threadIdx.x >> 6;
    const int gw   = blockIdx.x * WPB + wave;

    float l2_acc = 0.0f;   // per-lane masked Frobenius^2 partial
    float lp_acc = 0.0f;   // (lane 0 only) sum of logp[b, label[b]]
    float cr_acc = 0.0f;   // (lane 0 only) correct count

    for (int b = gw; b < Bc; b += NWAVES) {
        // ---- logits: argmax (first-index tie-break) + logsumexp ----
        float w = -INFINITY;
        if (lane < NAc) w = wts[(size_t)b * NAc + lane];
        float mv = w;
        int   mi = lane;
        for (int off = 32; off; off >>= 1) {
            float ov = __shfl_xor(mv, off, 64);
            int   oi = __shfl_xor(mi, off, 64);
            if (ov > mv || (ov == mv && oi < mi)) { mv = ov; mi = oi; }
        }
        float e  = (lane < NAc) ? expf(w - mv) : 0.0f;
        float se = e;
        for (int off = 32; off; off >>= 1) se += __shfl_xor(se, off, 64);
        float lse  = mv + logf(se);
        int   lab  = label[b];
        float wlab = __shfl(w, lab, 64);
        if (lane == 0) {
            lp_acc += wlab - lse;
            cr_acc += (mi == lab) ? 1.0f : 0.0f;
        }

        // ---- per-anchor rotmat from quaternion y[b, :, lane] ----
        if (lane < NAc) {
            const float* yb = y + (size_t)b * (NRc * NAc);
            float qw = yb[0 * NAc + lane];
            float qx = yb[1 * NAc + lane];
            float qy = yb[2 * NAc + lane];
            float qz = yb[3 * NAc + lane];
            float n   = sqrtf(qw * qw + qx * qx + qy * qy + qz * qz);
            float inv = 1.0f / fmaxf(n, 1e-8f);
            qw *= inv; qx *= inv; qy *= inv; qz *= inv;

            float R00 = 1.0f - 2.0f * (qy * qy + qz * qz);
            float R01 = 2.0f * (qx * qy - qz * qw);
            float R02 = 2.0f * (qx * qz + qy * qw);
            float R10 = 2.0f * (qx * qy + qz * qw);
            float R11 = 1.0f - 2.0f * (qx * qx + qz * qz);
            float R12 = 2.0f * (qy * qz - qx * qw);
            float R20 = 2.0f * (qx * qz - qy * qw);
            float R21 = 2.0f * (qy * qz + qx * qw);
            float R22 = 1.0f - 2.0f * (qx * qx + qy * qy);

            const float* g = gt_R + ((size_t)b * NAc + lane) * 9;
            float g0 = g[0], g1 = g[1], g2 = g[2];
            float g3 = g[3], g4 = g[4], g5 = g[5];
            float g6 = g[6], g7 = g[7], g8 = g[8];

            // mask = (acos(clip(0.5*(tr-1))) < 1) <=> 0.5*(tr-1) > cos(1)
            float xb = 0.5f * (g0 + g4 + g8 - 1.0f);
            if (xb > COS_ONE) {
                float d0 = g0 - R00, d1 = g1 - R01, d2 = g2 - R02;
                float d3 = g3 - R10, d4 = g4 - R11, d5 = g5 - R12;
                float d6 = g6 - R20, d7 = g7 - R21, d8 = g8 - R22;
                l2_acc += d0 * d0 + d1 * d1 + d2 * d2
                        + d3 * d3 + d4 * d4 + d5 * d5
                        + d6 * d6 + d7 * d7 + d8 * d8;
            }

            // ---- ang_err on the predicted lane ----
            if (lane == mi) {
                const float* A = anchors + (size_t)mi * 9;
                float a0 = A[0], a1 = A[1], a2 = A[2];
                float a3 = A[3], a4 = A[4], a5 = A[5];
                float a6 = A[6], a7 = A[7], a8 = A[8];
                // P = anchors[pred] @ sel   (sel = this lane's rotmat)
                float P00 = a0 * R00 + a1 * R10 + a2 * R20;
                float P01 = a0 * R01 + a1 * R11 + a2 * R21;
                float P02 = a0 * R02 + a1 * R12 + a2 * R22;
                float P10 = a3 * R00 + a4 * R10 + a5 * R20;
                float P11 = a3 * R01 + a4 * R11 + a5 * R21;
                float P12 = a3 * R02 + a4 * R12 + a5 * R22;
                float P20 = a6 * R00 + a7 * R10 + a8 * R20;
                float P21 = a6 * R01 + a7 * R11 + a8 * R21;
                float P22 = a6 * R02 + a7 * R12 + a8 * R22;
                // tr(P @ trueR^T) = sum_ij P[i][j] * trueR[i][j]
                const float* tR = gt_R + ((size_t)b * NAc + 29) * 9;
                float tr = P00 * tR[0] + P01 * tR[1] + P02 * tR[2]
                         + P10 * tR[3] + P11 * tR[4] + P12 * tR[5]
                         + P20 * tR[6] + P21 * tR[7] + P22 * tR[8];
                float cx = 0.5f * (tr - 1.0f);
                cx = fminf(fmaxf(cx, -1.0f + 1e-7f), 1.0f - 1e-7f);
                out[4 + b] = acosf(cx);
            }
        }
    }

    // ---- reduce partials: wave butterfly, then cross-wave via LDS ----
    for (int off = 32; off; off >>= 1) {
        l2_acc += __shfl_xor(l2_acc, off, 64);
        lp_acc += __shfl_xor(lp_acc, off, 64);
        cr_acc += __shfl_xor(cr_acc, off, 64);
    }
    __shared__ float s_l2[WPB], s_lp[WPB], s_cr[WPB];
    if (lane == 0) { s_l2[wave] = l2_acc; s_lp[wave] = lp_acc; s_cr[wave] = cr_acc; }
    __syncthreads();
    if (threadIdx.x == 0) {
        float t2 = 0.0f, tp = 0.0f, tc = 0.0f;
        for (int i = 0; i < WPB; ++i) { t2 += s_l2[i]; tp += s_lp[i]; tc += s_cr[i]; }
        l2p[blockIdx.x] = t2;
        lpp[blockIdx.x] = tp;
        crp[blockIdx.x] = tc;
    }
}

__global__ __launch_bounds__(64) void mtl_final(
    const float* __restrict__ l2p,
    const float* __restrict__ lpp,
    const float* __restrict__ crp,
    float*       __restrict__ out)
{
    const int lane = threadIdx.x;
    double l2 = 0.0, lp = 0.0, cr = 0.0;
    for (int i = lane; i < NBLK; i += 64) {
        l2 += (double)l2p[i];
        lp += (double)lpp[i];
        cr += (double)crp[i];
    }
    for (int off = 32; off; off >>= 1) {
        l2 += __shfl_xor(l2, off, 64);
        lp += __shfl_xor(lp, off, 64);
        cr += __shfl_xor(cr, off, 64);
    }
    if (lane == 0) {
        float cls = (float)(-lp / (double)Bc);
        float l2s = (float)(10.0 * l2);      // W_LOSS * l2_loss
        out[0] = cls + l2s;                  // loss
        out[1] = cls;                        // cls_loss
        out[2] = l2s;                        // W_LOSS * l2_loss
        out[3] = (float)(cr / (double)Bc);   // r_acc
    }
}

extern "C" void kernel_launch(void* const* d_in, const int* in_sizes, int n_in,
                              void* d_out, int out_size, void* d_ws, size_t ws_size,
                              hipStream_t stream) {
    const float* wts     = (const float*)d_in[0];
    const int*   label   = (const int*)d_in[1];
    const float* y       = (const float*)d_in[2];
    const float* gt_R    = (const float*)d_in[3];
    const float* anchors = (const float*)d_in[4];
    float* out = (float*)d_out;

    float* l2p = (float*)d_ws;        // NBLK floats
    float* lpp = l2p + NBLK;          // NBLK floats
    float* crp = lpp + NBLK;          // NBLK floats  (24 KB total)

    mtl_main<<<NBLK, 256, 0, stream>>>(wts, label, y, gt_R, anchors, out, l2p, lpp, crp);
    mtl_final<<<1, 64, 0, stream>>>(l2p, lpp, crp, out);
}